// Round 3
// baseline (211.745 us; speedup 1.0000x reference)
//
#include <hip/hip_runtime.h>

#define BATCH    8192
#define CTX      32
#define ROUTES   24
#define EDIM     128
#define NSLICE   24
#define WPB      4
#define NBLOCKS  (BATCH / WPB)

// One wave per batch row. Lanes split into two 32-lane halves; each half owns
// one full E=128 row per float4 load (32 x 16B = 512B coalesced). Dot
// reductions are 5-step butterflies within a half (each tree does TWO dots,
// one per half). Route and slice dots are interleaved in batches of 4 pairs
// (8 loads in flight, 8 independent shuffle chains) to maximize MLP/ILP.
__global__ __launch_bounds__(256, 5) void tale_fused(
    const int* __restrict__ context,            // (B, C)
    const int* __restrict__ route,              // (B, R)
    const int* __restrict__ lr,                 // (B, R)
    const int* __restrict__ slice_idx,          // (B,)
    const float* __restrict__ input_embed,      // (NUM_LOC, E)
    const float* __restrict__ inner_node_embed, // (NUM_INNER+1, E)
    const float* __restrict__ slice_node_embed, // (NSLICE, E)
    float* __restrict__ out)
{
    const int tid  = threadIdx.x;
    const int lane = tid & 63;
    const int half = lane >> 5;        // 0 = lower half, 1 = upper half
    const int sub  = lane & 31;        // owns dims 4*sub .. 4*sub+3
    const int w    = tid >> 6;
    const int b    = blockIdx.x * WPB + w;

    __shared__ float bs[WPB];

    // ---- per-row indices, one per lane; broadcast via shuffle at use ----
    int cidx = 0, ridx = 0, lridx = 0;
    if (lane < CTX) cidx = context[b * CTX + lane];
    if (lane < ROUTES) {
        ridx  = route[b * ROUTES + lane];
        lridx = lr[b * ROUTES + lane];
    }
    const int si = slice_idx[b];

    // ---- context embedding sum: 2 batches of 8 prefetched rows ----
    float4 acc = make_float4(0.f, 0.f, 0.f, 0.f);
    #pragma unroll
    for (int g = 0; g < 2; ++g) {
        float4 pv[8];
        #pragma unroll
        for (int j = 0; j < 8; ++j) {
            const int idx = __shfl(cidx, (half << 4) + g * 8 + j);
            pv[j] = *reinterpret_cast<const float4*>(
                input_embed + (size_t)idx * EDIM + (sub << 2));
        }
        #pragma unroll
        for (int j = 0; j < 8; ++j) {
            acc.x += pv[j].x; acc.y += pv[j].y;
            acc.z += pv[j].z; acc.w += pv[j].w;
        }
    }
    acc.x += __shfl_xor(acc.x, 32);
    acc.y += __shfl_xor(acc.y, 32);
    acc.z += __shfl_xor(acc.z, 32);
    acc.w += __shfl_xor(acc.w, 32);
    // lane now holds ctx[4*sub .. 4*sub+3]

    // ---- route + slice dots, interleaved: 3 batches x 4 (route,slice) pairs
    // half h handles route dot (2i+h) and slice logit (2i+h).
    float prodv = 1.f;
    float sd[12];          // slice logits for this half (uniform within half)
    float selv = 0.f;      // logit of target slice if it lives in this half
    #pragma unroll
    for (int bat = 0; bat < 3; ++bat) {
        float4 rv[4], sv[4];
        #pragma unroll
        for (int j = 0; j < 4; ++j) {
            const int i   = bat * 4 + j;
            const int d   = 2 * i + half;
            const int idx = __shfl(ridx, d);
            rv[j] = *reinterpret_cast<const float4*>(
                inner_node_embed + (size_t)idx * EDIM + (sub << 2));
            sv[j] = *reinterpret_cast<const float4*>(
                slice_node_embed + d * EDIM + (sub << 2));
        }
        float rp[4], sp[4];
        #pragma unroll
        for (int j = 0; j < 4; ++j) {
            rp[j] = rv[j].x * acc.x + rv[j].y * acc.y
                  + rv[j].z * acc.z + rv[j].w * acc.w;
            sp[j] = sv[j].x * acc.x + sv[j].y * acc.y
                  + sv[j].z * acc.z + sv[j].w * acc.w;
        }
        #pragma unroll
        for (int off = 16; off > 0; off >>= 1) {
            #pragma unroll
            for (int j = 0; j < 4; ++j) {
                rp[j] += __shfl_xor(rp[j], off);
                sp[j] += __shfl_xor(sp[j], off);
            }
        }
        #pragma unroll
        for (int j = 0; j < 4; ++j) {
            const int i   = bat * 4 + j;
            const int d   = 2 * i + half;
            const int idx = __shfl(ridx, d);
            const int l   = __shfl(lridx, d);
            const float sg = 1.f / (1.f + __expf(-rp[j]));
            float h = l ? sg : (1.f - sg);
            if (idx == 0) h = 1.f;       // padded route position
            prodv *= h;
            sd[i] = sp[j];
            if (d == si) selv = sp[j];
        }
    }
    prodv *= __shfl_xor(prodv, 32);      // even-half * odd-half products

    // ---- softmax over 24 logits: tree max, independent exps ----
    float m01 = fmaxf(sd[0], sd[1]),  m23 = fmaxf(sd[2], sd[3]);
    float m45 = fmaxf(sd[4], sd[5]),  m67 = fmaxf(sd[6], sd[7]);
    float m89 = fmaxf(sd[8], sd[9]),  mAB = fmaxf(sd[10], sd[11]);
    float mh = fmaxf(fmaxf(fmaxf(m01, m23), fmaxf(m45, m67)), fmaxf(m89, mAB));
    const float M = fmaxf(mh, __shfl_xor(mh, 32));
    float den = 0.f;
    #pragma unroll
    for (int i = 0; i < 12; ++i) den += __expf(sd[i] - M);
    den += __shfl_xor(den, 32);
    const float sel = __shfl(selv, (si & 1) << 5);
    const float slice_pre = __expf(sel - M) / den;

    const float pr = slice_pre * prodv;

    if (lane == 0) bs[w] = pr;
    __syncthreads();
    if (tid == 0) {
        const float s = bs[0] + bs[1] + bs[2] + bs[3];
        // out accumulates (1/NBLOCKS - blockSum/B) over blocks -> 1 - mean
        atomicAdd(out, 1.0f / NBLOCKS - s * (1.0f / BATCH));
    }
}

extern "C" void kernel_launch(void* const* d_in, const int* in_sizes, int n_in,
                              void* d_out, int out_size, void* d_ws, size_t ws_size,
                              hipStream_t stream)
{
    const int*   context          = (const int*)  d_in[0];
    const int*   route            = (const int*)  d_in[1];
    const int*   lr               = (const int*)  d_in[2];
    const int*   slice_idx        = (const int*)  d_in[3];
    const float* input_embed      = (const float*)d_in[4];
    const float* inner_node_embed = (const float*)d_in[5];
    const float* slice_node_embed = (const float*)d_in[6];
    float* out = (float*)d_out;

    // d_out is poisoned 0xAA before every launch; zero it, then blocks
    // atomic-accumulate so the final value is 1 - mean.
    hipMemsetAsync(out, 0, sizeof(float), stream);

    tale_fused<<<NBLOCKS, 64 * WPB, 0, stream>>>(
        context, route, lr, slice_idx,
        input_embed, inner_node_embed, slice_node_embed, out);
}